// Round 8
// baseline (276.680 us; speedup 1.0000x reference)
//
#include <hip/hip_runtime.h>
#include <hip/hip_bf16.h>
#include <math.h>

// Problem constants (reference: B=2, T=2048, D=1024, H=16, DH=64)
#define B_  2
#define T_  2048
#define D_  1024
#define H_  16
#define DH_ 64
#define WN_ (D_ * D_)   // 1,048,576 elems per weight

typedef __attribute__((ext_vector_type(8))) short bf16x8;
typedef __attribute__((ext_vector_type(4))) float f32x4;
typedef __attribute__((ext_vector_type(16))) float f32x16;

// async global->LDS, 16B per lane; dest = wave-uniform base + lane*16
__device__ __forceinline__ void gll16(const void* g, void* l) {
  __builtin_amdgcn_global_load_lds(
      (const __attribute__((address_space(1))) void*)g,
      (__attribute__((address_space(3))) void*)l, 16, 0, 0);
}

__device__ __forceinline__ void storeC(float* p, float v) { *p = v; }
__device__ __forceinline__ void storeC(__hip_bfloat16* p, float v) {
  *p = __float2bfloat16(v);
}

// ---------------------------------------------------------------------------
// f32 -> bf16 elementwise convert (4 elems/thread)
// ---------------------------------------------------------------------------
__global__ __launch_bounds__(256)
void cvt_f32_bf16(const float* __restrict__ in, __hip_bfloat16* __restrict__ out,
                  int n4) {
  const int i = blockIdx.x * 256 + threadIdx.x;
  if (i >= n4) return;
  const float4 a = ((const float4*)in)[i];
  __hip_bfloat16 h0 = __float2bfloat16(a.x);
  __hip_bfloat16 h1 = __float2bfloat16(a.y);
  __hip_bfloat16 h2 = __float2bfloat16(a.z);
  __hip_bfloat16 h3 = __float2bfloat16(a.w);
  ushort4 o;
  o.x = *(unsigned short*)&h0;
  o.y = *(unsigned short*)&h1;
  o.z = *(unsigned short*)&h2;
  o.w = *(unsigned short*)&h3;
  *(ushort4*)(out + (size_t)i * 4) = o;
}

// ---------------------------------------------------------------------------
// Wq|Wk|Wv f32 -> one contiguous bf16 [3072][1024]
// ---------------------------------------------------------------------------
__global__ __launch_bounds__(256)
void cvt3_w(const float* __restrict__ Wq, const float* __restrict__ Wk,
            const float* __restrict__ Wv, __hip_bfloat16* __restrict__ out) {
  const int i = blockIdx.x * 256 + threadIdx.x;  // over 3*WN_/4
  const int per = WN_ / 4;                       // 262144 (pow2)
  const int sel = i >> 18;                       // i / per
  const int off = i & (per - 1);
  const float* src = sel == 0 ? Wq : (sel == 1 ? Wk : Wv);
  const float4 a = ((const float4*)src)[off];
  __hip_bfloat16 h0 = __float2bfloat16(a.x);
  __hip_bfloat16 h1 = __float2bfloat16(a.y);
  __hip_bfloat16 h2 = __float2bfloat16(a.z);
  __hip_bfloat16 h3 = __float2bfloat16(a.w);
  ushort4 o;
  o.x = *(unsigned short*)&h0;
  o.y = *(unsigned short*)&h1;
  o.z = *(unsigned short*)&h2;
  o.w = *(unsigned short*)&h3;
  *(ushort4*)(out + (size_t)sel * WN_ + (size_t)off * 4) = o;
}

// ---------------------------------------------------------------------------
// bf16 MFMA GEMM: C[m,n] = sum_k A[m,k]*W[n,k]; C fp32 or bf16.
// 128x128 tile, BK=32, 256 thr = 4 waves. (verified R6/R7, unchanged)
// ---------------------------------------------------------------------------
template <typename CT>
__global__ __launch_bounds__(256)
void gemm_bf16_mfma(const __hip_bfloat16* __restrict__ A,
                    const __hip_bfloat16* __restrict__ W,
                    CT* __restrict__ C, int M, int N, int K) {
  __shared__ unsigned short As[128 * 32];
  __shared__ unsigned short Bs[128 * 32];
  const int tid = threadIdx.x;
  const int w = tid >> 6;
  const int lane = tid & 63;
  const int lg = lane >> 4;
  const int ln = lane & 15;
  const int wr = w >> 1, wc = w & 1;
  const int row0 = blockIdx.y * 128;
  const int col0 = blockIdx.x * 128;

  const int sr = w * 32 + (lane >> 2);
  const int sp = lane & 3;

  f32x4 acc[4][4];
#pragma unroll
  for (int m = 0; m < 4; ++m)
#pragma unroll
    for (int n = 0; n < 4; ++n) acc[m][n] = (f32x4){0.f, 0.f, 0.f, 0.f};

  for (int k0 = 0; k0 < K; k0 += 32) {
#pragma unroll
    for (int c = 0; c < 2; ++c) {
      const int r = sr + c * 16;
      const int ks = sp ^ ((r >> 1) & 3);
      gll16(A + (size_t)(row0 + r) * K + k0 + ks * 8,
            &As[(w * 32 + c * 16) * 32]);
      gll16(W + (size_t)(col0 + r) * K + k0 + ks * 8,
            &Bs[(w * 32 + c * 16) * 32]);
    }
    __syncthreads();

    bf16x8 af[4], bfr[4];
#pragma unroll
    for (int m = 0; m < 4; ++m) {
      const int r = wr * 64 + m * 16 + ln;
      af[m] = *(const bf16x8*)&As[r * 32 + (lg ^ ((r >> 1) & 3)) * 8];
    }
#pragma unroll
    for (int n = 0; n < 4; ++n) {
      const int r = wc * 64 + n * 16 + ln;
      bfr[n] = *(const bf16x8*)&Bs[r * 32 + (lg ^ ((r >> 1) & 3)) * 8];
    }
#pragma unroll
    for (int m = 0; m < 4; ++m)
#pragma unroll
      for (int n = 0; n < 4; ++n)
        acc[m][n] = __builtin_amdgcn_mfma_f32_16x16x32_bf16(af[m], bfr[n],
                                                            acc[m][n], 0, 0, 0);
    __syncthreads();
  }

#pragma unroll
  for (int m = 0; m < 4; ++m) {
#pragma unroll
    for (int reg = 0; reg < 4; ++reg) {
      CT* crow = C + (size_t)(row0 + wr * 64 + m * 16 + lg * 4 + reg) * N
                 + col0 + wc * 64;
#pragma unroll
      for (int n = 0; n < 4; ++n) storeC(&crow[n * 16 + ln], acc[m][n][reg]);
    }
  }
}

// ---------------------------------------------------------------------------
// RoPE on bf16 qkv[:, 0:2048] -> qb, kb [B,T,H,64] bf16. Q scaled by 0.125.
// ---------------------------------------------------------------------------
__global__ __launch_bounds__(256)
void rope_qkv(const __hip_bfloat16* __restrict__ qkv,
              __hip_bfloat16* __restrict__ Qb, __hip_bfloat16* __restrict__ Kb) {
  const int idx = blockIdx.x * 256 + threadIdx.x;  // B*T*H*32 threads
  const int i = idx & 31;
  const int rest = idx >> 5;            // (b*T + t)*H + h
  const int row = rest >> 4;            // b*T + t
  const int h = rest & 15;
  const int t = row & (T_ - 1);
  const float inv_freq = powf(10000.0f, -(float)i * (1.0f / 32.0f));
  const float ang = (float)t * inv_freq;
  const float c = cosf(ang), s = sinf(ang);
  const size_t rb = (size_t)row * 3072 + h * 64;
  const float q1 = __bfloat162float(qkv[rb + i]);
  const float q2 = __bfloat162float(qkv[rb + i + 32]);
  const float k1 = __bfloat162float(qkv[rb + 1024 + i]);
  const float k2 = __bfloat162float(qkv[rb + 1024 + i + 32]);
  const size_t base = (size_t)rest * DH_;
  Qb[base + i]      = __float2bfloat16((q1 * c - q2 * s) * 0.125f);
  Qb[base + i + 32] = __float2bfloat16((q2 * c + q1 * s) * 0.125f);
  Kb[base + i]      = __float2bfloat16(k1 * c - k2 * s);
  Kb[base + i + 32] = __float2bfloat16(k2 * c + k1 * s);
}

// ---------------------------------------------------------------------------
// V transpose: qkv[:, 2048:3072] bf16 -> vt [B,H,64,T] bf16 (one-time).
// ---------------------------------------------------------------------------
__global__ __launch_bounds__(256)
void vt_prep(const __hip_bfloat16* __restrict__ qkv,
             __hip_bfloat16* __restrict__ vt) {
  __shared__ unsigned short Ls[64][65];
  const int tt = blockIdx.x;       // t-tile
  const int bh = blockIdx.y;
  const int b = bh >> 4, h = bh & 15;
  const int tid = threadIdx.x;
  const int t0 = tt * 64;
  const int rb = tid >> 3, c0 = (tid & 7) * 8;
#pragma unroll
  for (int it = 0; it < 2; ++it) {
    const int r = it * 32 + rb;  // token row
    uint4 x = *(const uint4*)&qkv[(size_t)(b * T_ + t0 + r) * 3072 + 2048 +
                                  h * 64 + c0];
    const unsigned short* xs = (const unsigned short*)&x;
#pragma unroll
    for (int j = 0; j < 8; ++j) Ls[c0 + j][r] = xs[j];
  }
  __syncthreads();
  const int d = tid >> 2, t8 = (tid & 3) * 16;
  unsigned short tmp[16];
#pragma unroll
  for (int j = 0; j < 16; ++j) tmp[j] = Ls[d][t8 + j];
  __hip_bfloat16* dst = vt + ((size_t)(b * H_ + h) * 64 + d) * T_ + t0 + t8;
  *(uint4*)&dst[0] = *(uint4*)&tmp[0];
  *(uint4*)&dst[8] = *(uint4*)&tmp[8];
}

// ---------------------------------------------------------------------------
// Flash attention, swapped-operand 32x32x16 MFMA (R8 structure).
//  Block: 128 thr = 2 waves; wave owns 32 q-rows; q-tile 64; kv-tile 64.
//  S^T = mfma(K-frag, Q-frag): C/D col = lane&31 = q  ->  softmax lane-local
//  (31 in-lane fmax + one shfl_xor(32)); m/l/alpha/accO-rescale lane-local.
//  PV as O^T = mfma(V^T-frag, P-frag); P via per-wave LDS strip (8B packed
//  writes).  K/V LDS double-buffered, reg-prefetch 2 tiles ahead, one
//  barrier per kv-tile.  32x32 C/D layout (m74/m101): col=lane&31,
//  row=(reg&3)+8*(reg>>2)+4*(lane>>5).  A/B frag: row(col)=lane&31,
//  k=(lane>>5)*8+i.
// ---------------------------------------------------------------------------
#define SWZ(row, col) ((col) ^ (((row) & 7) << 3))

__global__ __launch_bounds__(128)
void attn_mfma32(const __hip_bfloat16* __restrict__ Qb,
                 const __hip_bfloat16* __restrict__ Kb,
                 const __hip_bfloat16* __restrict__ vt,
                 __hip_bfloat16* __restrict__ O) {
  __shared__ unsigned short Ks[2][64 * 64];
  __shared__ unsigned short Vs[2][64 * 64];   // V^T tile [d][key]
  __shared__ unsigned short Ps[2][32 * 64];   // per-wave P strip [q][key]

  const int bx = blockIdx.x;       // 0..15
  const int bh = blockIdx.y;
  const int b = bh >> 4, h = bh & 15;
  const int tid = threadIdx.x;
  const int w = tid >> 6;          // wave 0,1
  const int lane = tid & 63;
  const int lq = lane & 31;        // q-col / key-row / d-row owner
  const int hi = lane >> 5;

  const size_t headoff = (size_t)b * T_ * D_ + (size_t)h * DH_;
  const __hip_bfloat16* Qg = Qb + headoff;
  const __hip_bfloat16* Kg = Kb + headoff;
  const __hip_bfloat16* vtg = vt + (size_t)(b * H_ + h) * 64 * T_;
  __hip_bfloat16* Og = O + headoff;

  // staging map: thread covers tile rows sr0+{0,16,32,48}, 8-elem col sc0
  const int sr0 = tid >> 3;        // 0..15
  const int sc0 = (tid & 7) * 8;   // 0..56

  for (int pass = 0; pass < 2; ++pass) {
    const int qt = pass ? bx : 31 - bx;   // heavy q-tile first
    const int q_glob = qt * 64 + w * 32 + lq;

    // Q B-frags (4 dh-slices of 16) straight from global
    bf16x8 qf[4];
#pragma unroll
    for (int ks = 0; ks < 4; ++ks)
      qf[ks] = *(const bf16x8*)(Qg + (size_t)q_glob * D_ + ks * 16 + hi * 8);

    // prologue: tile0 -> LDS[0]; tile1 -> regs
    uint4 kreg[4], vreg[4];
#pragma unroll
    for (int it = 0; it < 4; ++it) {
      const int r = sr0 + it * 16;
      kreg[it] = *(const uint4*)(Kg + (size_t)r * D_ + sc0);
      vreg[it] = *(const uint4*)(vtg + (size_t)r * T_ + sc0);
    }
#pragma unroll
    for (int it = 0; it < 4; ++it) {
      const int r = sr0 + it * 16;
      *(uint4*)&Ks[0][r * 64 + SWZ(r, sc0)] = kreg[it];
      *(uint4*)&Vs[0][r * 64 + SWZ(r, sc0)] = vreg[it];
    }
    if (qt >= 1) {
#pragma unroll
      for (int it = 0; it < 4; ++it) {
        const int r = sr0 + it * 16;
        kreg[it] = *(const uint4*)(Kg + (size_t)(64 + r) * D_ + sc0);
        vreg[it] = *(const uint4*)(vtg + (size_t)r * T_ + 64 + sc0);
      }
    }

    float m_run = -3.0e38f, l_run = 0.f;
    f32x16 accO[2];
#pragma unroll
    for (int reg = 0; reg < 16; ++reg) { accO[0][reg] = 0.f; accO[1][reg] = 0.f; }

    __syncthreads();  // LDS[0] ready

    for (int kt = 0; kt <= qt; ++kt) {
      const int buf = kt & 1;
      // write next tile regs -> LDS[buf^1] (freed by last iteration's barrier)
      if (kt + 1 <= qt) {
#pragma unroll
        for (int it = 0; it < 4; ++it) {
          const int r = sr0 + it * 16;
          *(uint4*)&Ks[buf ^ 1][r * 64 + SWZ(r, sc0)] = kreg[it];
          *(uint4*)&Vs[buf ^ 1][r * 64 + SWZ(r, sc0)] = vreg[it];
        }
      }
      // issue loads for tile kt+2 (land during next iteration)
      if (kt + 2 <= qt) {
#pragma unroll
        for (int it = 0; it < 4; ++it) {
          const int r = sr0 + it * 16;
          kreg[it] = *(const uint4*)(Kg + (size_t)((kt + 2) * 64 + r) * D_ + sc0);
          vreg[it] = *(const uint4*)(vtg + (size_t)r * T_ + (kt + 2) * 64 + sc0);
        }
      }

      // ---- S^T = K · Q^T  (D[key][q], col = q = lane&31) ----
      f32x16 sf[2];
#pragma unroll
      for (int reg = 0; reg < 16; ++reg) { sf[0][reg] = 0.f; sf[1][reg] = 0.f; }
#pragma unroll
      for (int ks = 0; ks < 4; ++ks) {
        const int c = ks * 16 + hi * 8;
        bf16x8 ka0 = *(const bf16x8*)&Ks[buf][lq * 64 + SWZ(lq, c)];
        bf16x8 ka1 = *(const bf16x8*)&Ks[buf][(32 + lq) * 64 + SWZ(32 + lq, c)];
        sf[0] = __builtin_amdgcn_mfma_f32_32x32x16_bf16(ka0, qf[ks], sf[0], 0, 0, 0);
        sf[1] = __builtin_amdgcn_mfma_f32_32x32x16_bf16(ka1, qf[ks], sf[1], 0, 0, 0);
      }

      // ---- causal mask (diagonal tile only) ----
      const int kv0 = kt * 64;
      if (kt == qt) {
#pragma unroll
        for (int reg = 0; reg < 16; ++reg) {
          const int krow = (reg & 3) + 8 * (reg >> 2) + 4 * hi;
          if (kv0 + krow > q_glob)      sf[0][reg] = -3.0e38f;
          if (kv0 + 32 + krow > q_glob) sf[1][reg] = -3.0e38f;
        }
      }

      // ---- online softmax (all lane-local; one cross-half shfl each) ----
      float pmax = -3.0e38f;
#pragma unroll
      for (int reg = 0; reg < 16; ++reg)
        pmax = fmaxf(pmax, fmaxf(sf[0][reg], sf[1][reg]));
      pmax = fmaxf(pmax, __shfl_xor(pmax, 32, 64));
      const float mnew = fmaxf(m_run, pmax);
      const float alpha = __expf(m_run - mnew);
      m_run = mnew;
      float rsum = 0.f;
#pragma unroll
      for (int reg = 0; reg < 16; ++reg) {
        sf[0][reg] = __expf(sf[0][reg] - mnew);
        sf[1][reg] = __expf(sf[1][reg] - mnew);
        rsum += sf[0][reg] + sf[1][reg];
      }
      rsum += __shfl_xor(rsum, 32, 64);
      l_run = l_run * alpha + rsum;
#pragma unroll
      for (int reg = 0; reg < 16; ++reg) {
        accO[0][reg] *= alpha;
        accO[1][reg] *= alpha;
      }

      // ---- P -> per-wave LDS strip (packed 8B writes) ----
#pragma unroll
      for (int kb = 0; kb < 2; ++kb) {
#pragma unroll
        for (int j = 0; j < 4; ++j) {
          __hip_bfloat16 b0 = __float2bfloat16(sf[kb][4 * j + 0]);
          __hip_bfloat16 b1 = __float2bfloat16(sf[kb][4 * j + 1]);
          __hip_bfloat16 b2 = __float2bfloat16(sf[kb][4 * j + 2]);
          __hip_bfloat16 b3 = __float2bfloat16(sf[kb][4 * j + 3]);
          uint2 pk;
          pk.x = (unsigned)*(unsigned short*)&b0 |
                 ((unsigned)*(unsigned short*)&b1 << 16);
          pk.y = (unsigned)*(unsigned short*)&b2 |
                 ((unsigned)*(unsigned short*)&b3 << 16);
          const int col = kb * 32 + 8 * j + 4 * hi;   // keys kb*32+8j+4hi+0..3
          *(uint2*)&Ps[w][lq * 64 + SWZ(lq, col)] = pk;
        }
      }

      // ---- O^T += V^T · P  (D[d][q], col = q) ----
#pragma unroll
      for (int ks = 0; ks < 4; ++ks) {
        const int c = ks * 16 + hi * 8;
        bf16x8 pb  = *(const bf16x8*)&Ps[w][lq * 64 + SWZ(lq, c)];
        bf16x8 va0 = *(const bf16x8*)&Vs[buf][lq * 64 + SWZ(lq, c)];
        bf16x8 va1 = *(const bf16x8*)&Vs[buf][(32 + lq) * 64 + SWZ(32 + lq, c)];
        accO[0] = __builtin_amdgcn_mfma_f32_32x32x16_bf16(va0, pb, accO[0], 0, 0, 0);
        accO[1] = __builtin_amdgcn_mfma_f32_32x32x16_bf16(va1, pb, accO[1], 0, 0, 0);
      }

      __syncthreads();  // all done with LDS[buf] and writes to LDS[buf^1]
    }

    // ---- epilogue: O[q][d] = accO^T / l ----
    const float inv = 1.0f / l_run;
#pragma unroll
    for (int db = 0; db < 2; ++db) {
#pragma unroll
      for (int j = 0; j < 4; ++j) {
        __hip_bfloat16 b0 = __float2bfloat16(accO[db][4 * j + 0] * inv);
        __hip_bfloat16 b1 = __float2bfloat16(accO[db][4 * j + 1] * inv);
        __hip_bfloat16 b2 = __float2bfloat16(accO[db][4 * j + 2] * inv);
        __hip_bfloat16 b3 = __float2bfloat16(accO[db][4 * j + 3] * inv);
        uint2 pk;
        pk.x = (unsigned)*(unsigned short*)&b0 |
               ((unsigned)*(unsigned short*)&b1 << 16);
        pk.y = (unsigned)*(unsigned short*)&b2 |
               ((unsigned)*(unsigned short*)&b3 << 16);
        const int d = db * 32 + 8 * j + 4 * hi;
        *(uint2*)(Og + (size_t)q_glob * D_ + d) = pk;
      }
    }
  }
}

// ---------------------------------------------------------------------------
// kernel_launch. ws layout identical to R7 (peak 65.1 MB, proven):
//   qkvb bf16 [4096,3072] -> aob | xb | Wqkvb -> Wob | qb | kb | vt
// ---------------------------------------------------------------------------
extern "C" void kernel_launch(void* const* d_in, const int* in_sizes, int n_in,
                              void* d_out, int out_size, void* d_ws, size_t ws_size,
                              hipStream_t stream) {
  const float* x  = (const float*)d_in[0];
  const float* Wq = (const float*)d_in[1];
  const float* Wk = (const float*)d_in[2];
  const float* Wv = (const float*)d_in[3];
  const float* Wo = (const float*)d_in[4];
  float* out = (float*)d_out;

  const size_t NE = (size_t)B_ * T_ * D_;   // 4,194,304
  char* base = (char*)d_ws;
  __hip_bfloat16* qkvb  = (__hip_bfloat16*)base;                    // 3*NE el
  __hip_bfloat16* xb    = (__hip_bfloat16*)(base + 3 * NE * 2);     // NE el
  __hip_bfloat16* Wqkvb = (__hip_bfloat16*)(base + 4 * NE * 2);     // 3*WN_ el
  __hip_bfloat16* qb    = (__hip_bfloat16*)(base + 4 * NE * 2 + 3ull * WN_ * 2);
  __hip_bfloat16* kb    = qb + NE;
  __hip_bfloat16* vtb   = kb + NE;
  __hip_bfloat16* aob   = qkvb;   // overlays qkvb (dead after rope+vt_prep)
  __hip_bfloat16* Wob   = Wqkvb;  // overlays Wqkvb (dead after gemm_qkv)

  cvt_f32_bf16<<<(int)(NE / 4 / 256), 256, 0, stream>>>(x, xb, (int)(NE / 4));
  cvt3_w<<<3 * WN_ / 4 / 256, 256, 0, stream>>>(Wq, Wk, Wv, Wqkvb);

  const dim3 gq(3 * D_ / 128, (B_ * T_) / 128);  // (24, 32)
  gemm_bf16_mfma<__hip_bfloat16><<<gq, 256, 0, stream>>>(
      xb, Wqkvb, qkvb, B_ * T_, 3 * D_, D_);

  rope_qkv<<<(B_ * T_ * H_ * 32) / 256, 256, 0, stream>>>(qkvb, qb, kb);
  vt_prep<<<dim3(T_ / 64, B_ * H_), 256, 0, stream>>>(qkvb, vtb);

  const dim3 ga(T_ / 128, B_ * H_);  // (16, 32) paired q-tiles
  attn_mfma32<<<ga, 128, 0, stream>>>(qb, kb, vtb, aob);

  cvt_f32_bf16<<<WN_ / 4 / 256, 256, 0, stream>>>(Wo, Wob, WN_ / 4);

  const dim3 go(D_ / 128, (B_ * T_) / 128);  // (8, 32)
  gemm_bf16_mfma<float><<<go, 256, 0, stream>>>(aob, Wob, out, B_ * T_, D_, D_);
}

// Round 10
// 233.965 us; speedup vs baseline: 1.1826x; 1.1826x over previous
//
#include <hip/hip_runtime.h>
#include <hip/hip_bf16.h>
#include <math.h>

// Problem constants (reference: B=2, T=2048, D=1024, H=16, DH=64)
#define B_  2
#define T_  2048
#define D_  1024
#define H_  16
#define DH_ 64
#define WN_ (D_ * D_)   // 1,048,576 elems per weight

typedef __attribute__((ext_vector_type(8))) short bf16x8;
typedef __attribute__((ext_vector_type(4))) float f32x4;
typedef __attribute__((ext_vector_type(16))) float f32x16;

// async global->LDS, 16B per lane; dest = wave-uniform base + lane*16
__device__ __forceinline__ void gll16(const void* g, void* l) {
  __builtin_amdgcn_global_load_lds(
      (const __attribute__((address_space(1))) void*)g,
      (__attribute__((address_space(3))) void*)l, 16, 0, 0);
}

__device__ __forceinline__ void storeC(float* p, float v) { *p = v; }
__device__ __forceinline__ void storeC(__hip_bfloat16* p, float v) {
  *p = __float2bfloat16(v);
}

// ---------------------------------------------------------------------------
// f32 -> bf16 elementwise convert (4 elems/thread)
// ---------------------------------------------------------------------------
__global__ __launch_bounds__(256)
void cvt_f32_bf16(const float* __restrict__ in, __hip_bfloat16* __restrict__ out,
                  int n4) {
  const int i = blockIdx.x * 256 + threadIdx.x;
  if (i >= n4) return;
  const float4 a = ((const float4*)in)[i];
  __hip_bfloat16 h0 = __float2bfloat16(a.x);
  __hip_bfloat16 h1 = __float2bfloat16(a.y);
  __hip_bfloat16 h2 = __float2bfloat16(a.z);
  __hip_bfloat16 h3 = __float2bfloat16(a.w);
  ushort4 o;
  o.x = *(unsigned short*)&h0;
  o.y = *(unsigned short*)&h1;
  o.z = *(unsigned short*)&h2;
  o.w = *(unsigned short*)&h3;
  *(ushort4*)(out + (size_t)i * 4) = o;
}

// ---------------------------------------------------------------------------
// Wq|Wk|Wv f32 -> one contiguous bf16 [3072][1024]
// ---------------------------------------------------------------------------
__global__ __launch_bounds__(256)
void cvt3_w(const float* __restrict__ Wq, const float* __restrict__ Wk,
            const float* __restrict__ Wv, __hip_bfloat16* __restrict__ out) {
  const int i = blockIdx.x * 256 + threadIdx.x;  // over 3*WN_/4
  const int per = WN_ / 4;                       // 262144 (pow2)
  const int sel = i >> 18;
  const int off = i & (per - 1);
  const float* src = sel == 0 ? Wq : (sel == 1 ? Wk : Wv);
  const float4 a = ((const float4*)src)[off];
  __hip_bfloat16 h0 = __float2bfloat16(a.x);
  __hip_bfloat16 h1 = __float2bfloat16(a.y);
  __hip_bfloat16 h2 = __float2bfloat16(a.z);
  __hip_bfloat16 h3 = __float2bfloat16(a.w);
  ushort4 o;
  o.x = *(unsigned short*)&h0;
  o.y = *(unsigned short*)&h1;
  o.z = *(unsigned short*)&h2;
  o.w = *(unsigned short*)&h3;
  *(ushort4*)(out + (size_t)sel * WN_ + (size_t)off * 4) = o;
}

// ---------------------------------------------------------------------------
// bf16 MFMA GEMM: C[m,n] = sum_k A[m,k]*W[n,k]; C fp32 or bf16.
// 128x128 tile, BK=32, 256 thr = 4 waves. (verified R6/R7/R8, unchanged)
// ---------------------------------------------------------------------------
template <typename CT>
__global__ __launch_bounds__(256)
void gemm_bf16_mfma(const __hip_bfloat16* __restrict__ A,
                    const __hip_bfloat16* __restrict__ W,
                    CT* __restrict__ C, int M, int N, int K) {
  __shared__ unsigned short As[128 * 32];
  __shared__ unsigned short Bs[128 * 32];
  const int tid = threadIdx.x;
  const int w = tid >> 6;
  const int lane = tid & 63;
  const int lg = lane >> 4;
  const int ln = lane & 15;
  const int wr = w >> 1, wc = w & 1;
  const int row0 = blockIdx.y * 128;
  const int col0 = blockIdx.x * 128;

  const int sr = w * 32 + (lane >> 2);
  const int sp = lane & 3;

  f32x4 acc[4][4];
#pragma unroll
  for (int m = 0; m < 4; ++m)
#pragma unroll
    for (int n = 0; n < 4; ++n) acc[m][n] = (f32x4){0.f, 0.f, 0.f, 0.f};

  for (int k0 = 0; k0 < K; k0 += 32) {
#pragma unroll
    for (int c = 0; c < 2; ++c) {
      const int r = sr + c * 16;
      const int ks = sp ^ ((r >> 1) & 3);
      gll16(A + (size_t)(row0 + r) * K + k0 + ks * 8,
            &As[(w * 32 + c * 16) * 32]);
      gll16(W + (size_t)(col0 + r) * K + k0 + ks * 8,
            &Bs[(w * 32 + c * 16) * 32]);
    }
    __syncthreads();

    bf16x8 af[4], bfr[4];
#pragma unroll
    for (int m = 0; m < 4; ++m) {
      const int r = wr * 64 + m * 16 + ln;
      af[m] = *(const bf16x8*)&As[r * 32 + (lg ^ ((r >> 1) & 3)) * 8];
    }
#pragma unroll
    for (int n = 0; n < 4; ++n) {
      const int r = wc * 64 + n * 16 + ln;
      bfr[n] = *(const bf16x8*)&Bs[r * 32 + (lg ^ ((r >> 1) & 3)) * 8];
    }
#pragma unroll
    for (int m = 0; m < 4; ++m)
#pragma unroll
      for (int n = 0; n < 4; ++n)
        acc[m][n] = __builtin_amdgcn_mfma_f32_16x16x32_bf16(af[m], bfr[n],
                                                            acc[m][n], 0, 0, 0);
    __syncthreads();
  }

#pragma unroll
  for (int m = 0; m < 4; ++m) {
#pragma unroll
    for (int reg = 0; reg < 4; ++reg) {
      CT* crow = C + (size_t)(row0 + wr * 64 + m * 16 + lg * 4 + reg) * N
                 + col0 + wc * 64;
#pragma unroll
      for (int n = 0; n < 4; ++n) storeC(&crow[n * 16 + ln], acc[m][n][reg]);
    }
  }
}

// ---------------------------------------------------------------------------
// RoPE on bf16 qkv[:, 0:2048] -> qb, kb [B,T,H,64] bf16. Q scaled by 0.125.
// ---------------------------------------------------------------------------
__global__ __launch_bounds__(256)
void rope_qkv(const __hip_bfloat16* __restrict__ qkv,
              __hip_bfloat16* __restrict__ Qb, __hip_bfloat16* __restrict__ Kb) {
  const int idx = blockIdx.x * 256 + threadIdx.x;  // B*T*H*32 threads
  const int i = idx & 31;
  const int rest = idx >> 5;            // (b*T + t)*H + h
  const int row = rest >> 4;            // b*T + t
  const int h = rest & 15;
  const int t = row & (T_ - 1);
  const float inv_freq = powf(10000.0f, -(float)i * (1.0f / 32.0f));
  const float ang = (float)t * inv_freq;
  const float c = cosf(ang), s = sinf(ang);
  const size_t rb = (size_t)row * 3072 + h * 64;
  const float q1 = __bfloat162float(qkv[rb + i]);
  const float q2 = __bfloat162float(qkv[rb + i + 32]);
  const float k1 = __bfloat162float(qkv[rb + 1024 + i]);
  const float k2 = __bfloat162float(qkv[rb + 1024 + i + 32]);
  const size_t base = (size_t)rest * DH_;
  Qb[base + i]      = __float2bfloat16((q1 * c - q2 * s) * 0.125f);
  Qb[base + i + 32] = __float2bfloat16((q2 * c + q1 * s) * 0.125f);
  Kb[base + i]      = __float2bfloat16(k1 * c - k2 * s);
  Kb[base + i + 32] = __float2bfloat16(k2 * c + k1 * s);
}

// ---------------------------------------------------------------------------
// K -> fragment-major layout.  Frag (kb,ks), lane l=hi*32+lq holds
// K[kt*64 + kb*32 + lq][ks*16 + hi*8 + 0..8).  Flat elem offset per head:
//   kt*4096 + ((kb*4+ks)*64 + l)*8.
// ---------------------------------------------------------------------------
__global__ __launch_bounds__(256)
void kf_prep(const __hip_bfloat16* __restrict__ kb, __hip_bfloat16* __restrict__ Kf) {
  const int kt = blockIdx.x;        // 0..31
  const int bh = blockIdx.y;        // 0..31
  const int b = bh >> 4, h = bh & 15;
  const int tid = threadIdx.x;
  const int j = tid & 7;
  const int t0 = tid >> 3;          // 0..31
  __hip_bfloat16* dsth = Kf + (size_t)bh * (T_ * 64) + (size_t)kt * 4096;
#pragma unroll
  for (int it = 0; it < 2; ++it) {
    const int t = it * 32 + t0;
    bf16x8 x = *(const bf16x8*)(kb +
        (size_t)(((size_t)b * T_ + kt * 64 + t) * H_ + h) * 64 + j * 8);
    const int kb2 = t >> 5, lane31 = t & 31, ks = j >> 1, hi = j & 1;
    *(bf16x8*)(dsth + (((kb2 * 4 + ks) * 64 + hi * 32 + lane31) * 8)) = x;
  }
}

// ---------------------------------------------------------------------------
// V (qkv cols 2048..3071) -> V^T fragment-major.  Frag (kb,ks), lane l holds
// V^T[kb*32+lq][key = kt*64 + ks*16 + hi*8 + 0..8).  Same flat layout as Kf.
// ---------------------------------------------------------------------------
__global__ __launch_bounds__(256)
void vf_prep(const __hip_bfloat16* __restrict__ qkv, __hip_bfloat16* __restrict__ Vf) {
  __shared__ unsigned short Ls[64][72];   // [d][t], 144B rows (16B aligned)
  const int kt = blockIdx.x;
  const int bh = blockIdx.y;
  const int b = bh >> 4, h = bh & 15;
  const int tid = threadIdx.x;
  const int rb = tid >> 3, c0 = (tid & 7) * 8;
#pragma unroll
  for (int it = 0; it < 2; ++it) {
    const int r = it * 32 + rb;  // token row in tile
    uint4 x = *(const uint4*)&qkv[(size_t)((size_t)b * T_ + kt * 64 + r) * 3072 +
                                  2048 + h * 64 + c0];
    const unsigned short* xs = (const unsigned short*)&x;
#pragma unroll
    for (int q = 0; q < 8; ++q) Ls[c0 + q][r] = xs[q];
  }
  __syncthreads();
  __hip_bfloat16* dsth = Vf + (size_t)bh * (T_ * 64) + (size_t)kt * 4096;
#pragma unroll
  for (int e = 0; e < 2; ++e) {
    const int g = e * 256 + tid;            // 0..511 frag-groups
    const int lane31 = g & 31, hi = (g >> 5) & 1, ks = (g >> 6) & 3, kb2 = g >> 8;
    bf16x8 x = *(const bf16x8*)&Ls[kb2 * 32 + lane31][ks * 16 + hi * 8];
    *(bf16x8*)(dsth + (size_t)g * 8) = x;   // g*8 == ((kb2*4+ks)*64+hi*32+lane31)*8
  }
}

// ---------------------------------------------------------------------------
// Barrier-free flash attention (R9 structure, re-audited R9->R10).
//  One wave = 32 q-rows, fully independent: NO __syncthreads -> no vmcnt
//  drains; loads pipeline freely.  K/V register-resident (frag-major 1KB
//  coalesced loads), double-buffered 1 tile ahead.  P via per-wave LDS strip.
//  Compute core identical to R8-verified code.
// ---------------------------------------------------------------------------
#define SWZ(row, col) ((col) ^ (((row) & 7) << 3))

struct KV { bf16x8 k[2][4]; bf16x8 v[2][4]; };

__global__ __launch_bounds__(256, 2)
void attn_reg(const __hip_bfloat16* __restrict__ Qb,
              const __hip_bfloat16* __restrict__ Kf,
              const __hip_bfloat16* __restrict__ Vf,
              __hip_bfloat16* __restrict__ O) {
  __shared__ unsigned short Ps[4][32 * 64];  // per-wave P strip [q][key]

  const int bx = blockIdx.x;   // 0..15
  const int bh = blockIdx.y;   // 0..31
  const int b = bh >> 4, h = bh & 15;
  const int tid = threadIdx.x;
  const int w = tid >> 6;
  const int lane = tid & 63;
  const int lq = lane & 31;
  const int hi = lane >> 5;

  const int qu = (w < 2) ? (2 * bx + w) : (62 - 2 * bx + (w & 1));
  const int nt = (qu >> 1) + 1;           // kv-tiles of 64 keys
  const int q_glob = qu * 32 + lq;

  const size_t headoff = (size_t)b * T_ * D_ + (size_t)h * DH_;
  const __hip_bfloat16* Qg = Qb + headoff;
  const __hip_bfloat16* Kfh = Kf + (size_t)bh * (T_ * 64);
  const __hip_bfloat16* Vfh = Vf + (size_t)bh * (T_ * 64);
  __hip_bfloat16* Og = O + headoff;

  // Q B-frags (col=q, k=d): 4 x 16B
  bf16x8 qf[4];
#pragma unroll
  for (int ks = 0; ks < 4; ++ks)
    qf[ks] = *(const bf16x8*)(Qg + (size_t)q_glob * D_ + ks * 16 + hi * 8);

  float m_run = -3.0e38f, l_run = 0.f;
  f32x16 accO[2];
#pragma unroll
  for (int reg = 0; reg < 16; ++reg) { accO[0][reg] = 0.f; accO[1][reg] = 0.f; }

  auto load = [&](int kt) {
    KV r;
    const __hip_bfloat16* kp = Kfh + (size_t)kt * 4096;
    const __hip_bfloat16* vp = Vfh + (size_t)kt * 4096;
#pragma unroll
    for (int kb2 = 0; kb2 < 2; ++kb2)
#pragma unroll
      for (int ks = 0; ks < 4; ++ks) {
        r.k[kb2][ks] = *(const bf16x8*)(kp + ((kb2 * 4 + ks) * 64 + lane) * 8);
        r.v[kb2][ks] = *(const bf16x8*)(vp + ((kb2 * 4 + ks) * 64 + lane) * 8);
      }
    return r;
  };

  auto compute = [&](const KV& kv, int kt) {
    // ---- S^T = K · Q^T  (col = q = lq) ----
    f32x16 sf[2];
#pragma unroll
    for (int reg = 0; reg < 16; ++reg) { sf[0][reg] = 0.f; sf[1][reg] = 0.f; }
    const bool last = (kt == nt - 1);
    const bool skip1 = last && !(qu & 1);   // upper key-half fully masked
#pragma unroll
    for (int ks = 0; ks < 4; ++ks)
      sf[0] = __builtin_amdgcn_mfma_f32_32x32x16_bf16(kv.k[0][ks], qf[ks], sf[0], 0, 0, 0);
    if (!skip1) {
#pragma unroll
      for (int ks = 0; ks < 4; ++ks)
        sf[1] = __builtin_amdgcn_mfma_f32_32x32x16_bf16(kv.k[1][ks], qf[ks], sf[1], 0, 0, 0);
    }

    // ---- causal mask (last tile only; earlier tiles provably unmasked) ----
    if (last) {
      const int kv0 = kt * 64;
#pragma unroll
      for (int reg = 0; reg < 16; ++reg) {
        const int krow = (reg & 3) + 8 * (reg >> 2) + 4 * hi;
        if (kv0 + krow > q_glob)      sf[0][reg] = -3.0e38f;
        if (kv0 + 32 + krow > q_glob) sf[1][reg] = -3.0e38f;
      }
    }

    // ---- online softmax (lane-local; one cross-half shfl each) ----
    float pmax = -3.0e38f;
#pragma unroll
    for (int reg = 0; reg < 16; ++reg)
      pmax = fmaxf(pmax, fmaxf(sf[0][reg], sf[1][reg]));
    pmax = fmaxf(pmax, __shfl_xor(pmax, 32, 64));
    const float mnew = fmaxf(m_run, pmax);
    const float alpha = __expf(m_run - mnew);
    m_run = mnew;
    float rsum = 0.f;
#pragma unroll
    for (int reg = 0; reg < 16; ++reg) {
      sf[0][reg] = __expf(sf[0][reg] - mnew);
      sf[1][reg] = __expf(sf[1][reg] - mnew);
      rsum += sf[0][reg] + sf[1][reg];
    }
    rsum += __shfl_xor(rsum, 32, 64);
    l_run = l_run * alpha + rsum;
#pragma unroll
    for (int reg = 0; reg < 16; ++reg) {
      accO[0][reg] *= alpha;
      accO[1][reg] *= alpha;
    }

    // ---- P -> per-wave LDS strip (packed 8B writes) ----
#pragma unroll
    for (int kb2 = 0; kb2 < 2; ++kb2) {
#pragma unroll
      for (int j = 0; j < 4; ++j) {
        __hip_bfloat16 b0 = __float2bfloat16(sf[kb2][4 * j + 0]);
        __hip_bfloat16 b1 = __float2bfloat16(sf[kb2][4 * j + 1]);
        __hip_bfloat16 b2 = __float2bfloat16(sf[kb2][4 * j + 2]);
        __hip_bfloat16 b3 = __float2bfloat16(sf[kb2][4 * j + 3]);
        uint2 pk;
        pk.x = (unsigned)*(unsigned short*)&b0 |
               ((unsigned)*(unsigned short*)&b1 << 16);
        pk.y = (unsigned)*(unsigned short*)&b2 |
               ((unsigned)*(unsigned short*)&b3 << 16);
        const int col = kb2 * 32 + 8 * j + 4 * hi;
        *(uint2*)&Ps[w][lq * 64 + SWZ(lq, col)] = pk;
      }
    }

    // ---- O^T += V^T · P ----
#pragma unroll
    for (int ks = 0; ks < 4; ++ks) {
      const int c = ks * 16 + hi * 8;
      bf16x8 pb = *(const bf16x8*)&Ps[w][lq * 64 + SWZ(lq, c)];
      accO[0] = __builtin_amdgcn_mfma_f32_32x32x16_bf16(kv.v[0][ks], pb, accO[0], 0, 0, 0);
      accO[1] = __builtin_amdgcn_mfma_f32_32x32x16_bf16(kv.v[1][ks], pb, accO[1], 0, 0, 0);
    }
  };

  // ---- main loop: explicit 2-buffer rotation, loads 1 tile ahead ----
  KV bufA = load(0), bufB;
  int kt = 0;
  while (true) {
    if (kt + 1 < nt) bufB = load(kt + 1);
    compute(bufA, kt);
    ++kt; if (kt == nt) break;
    if (kt + 1 < nt) bufA = load(kt + 1);
    compute(bufB, kt);
    ++kt; if (kt == nt) break;
  }

  // ---- epilogue: O[q][d] = accO^T / l ----
  const float inv = 1.0f / l_run;
#pragma unroll
  for (int db = 0; db < 2; ++db) {
#pragma unroll
    for (int j = 0; j < 4; ++j) {
      __hip_bfloat16 b0 = __float2bfloat16(accO[db][4 * j + 0] * inv);
      __hip_bfloat16 b1 = __float2bfloat16(accO[db][4 * j + 1] * inv);
      __hip_bfloat16 b2 = __float2bfloat16(accO[db][4 * j + 2] * inv);
      __hip_bfloat16 b3 = __float2bfloat16(accO[db][4 * j + 3] * inv);
      uint2 pk;
      pk.x = (unsigned)*(unsigned short*)&b0 |
             ((unsigned)*(unsigned short*)&b1 << 16);
      pk.y = (unsigned)*(unsigned short*)&b2 |
             ((unsigned)*(unsigned short*)&b3 << 16);
      const int d = db * 32 + 8 * j + 4 * hi;
      *(uint2*)(Og + (size_t)q_glob * D_ + d) = pk;
    }
  }
}

// ---------------------------------------------------------------------------
// kernel_launch. ws elems (bf16): qkvb 3NE | xb NE | Wqkvb 3WN | qb NE |
// kb NE | Kf NE | Vf NE  = 2*(7NE+3WN) B = 65.0 MB (<= R7-proven 65.1).
// aob overlays qkvb; Wob overlays Wqkvb (stream-ordered reuse).
// ---------------------------------------------------------------------------
extern "C" void kernel_launch(void* const* d_in, const int* in_sizes, int n_in,
                              void* d_out, int out_size, void* d_ws, size_t ws_size,
                              hipStream_t stream) {
  const float* x  = (const float*)d_in[0];
  const float* Wq = (const float*)d_in[1];
  const float* Wk = (const float*)d_in[2];
  const float* Wv = (const float*)d_in[3];
  const float* Wo = (const float*)d_in[4];
  float* out = (float*)d_out;

  const size_t NE = (size_t)B_ * T_ * D_;   // 4,194,304
  char* base = (char*)d_ws;
  __hip_bfloat16* qkvb  = (__hip_bfloat16*)base;                          // 3NE
  __hip_bfloat16* xb    = (__hip_bfloat16*)(base + 3 * NE * 2);           // NE
  __hip_bfloat16* Wqkvb = (__hip_bfloat16*)(base + 4 * NE * 2);           // 3WN
  __hip_bfloat16* qb    = (__hip_bfloat16*)(base + 4 * NE * 2 + 3ull * WN_ * 2);
  __hip_bfloat16* kb    = qb + NE;
  __hip_bfloat16* Kfb   = kb + NE;
  __hip_bfloat16* Vfb   = Kfb + NE;
  __hip_bfloat16* aob   = qkvb;   // overlays qkvb (dead after rope+vf_prep)
  __hip_bfloat16* Wob   = Wqkvb;  // overlays Wqkvb (dead after gemm_qkv)

  cvt_f32_bf16<<<(int)(NE / 4 / 256), 256, 0, stream>>>(x, xb, (int)(NE / 4));
  cvt3_w<<<3 * WN_ / 4 / 256, 256, 0, stream>>>(Wq, Wk, Wv, Wqkvb);

  const dim3 gq(3 * D_ / 128, (B_ * T_) / 128);  // (24, 32)
  gemm_bf16_mfma<__hip_bfloat16><<<gq, 256, 0, stream>>>(
      xb, Wqkvb, qkvb, B_ * T_, 3 * D_, D_);

  rope_qkv<<<(B_ * T_ * H_ * 32) / 256, 256, 0, stream>>>(qkvb, qb, kb);
  kf_prep<<<dim3(T_ / 64, B_ * H_), 256, 0, stream>>>(kb, Kfb);
  vf_prep<<<dim3(T_ / 64, B_ * H_), 256, 0, stream>>>(qkvb, Vfb);

  const dim3 ga(16, B_ * H_);  // 512 blocks x 4 independent waves
  attn_reg<<<ga, 256, 0, stream>>>(qb, Kfb, Vfb, aob);

  cvt_f32_bf16<<<WN_ / 4 / 256, 256, 0, stream>>>(Wo, Wob, WN_ / 4);

  const dim3 go(D_ / 128, (B_ * T_) / 128);  // (8, 32)
  gemm_bf16_mfma<float><<<go, 256, 0, stream>>>(aob, Wob, out, B_ * T_, D_, D_);
}